// Round 1
// baseline (312.074 us; speedup 1.0000x reference)
//
#include <hip/hip_runtime.h>

#define S_LEN 16
#define NMODEL 4096
#define DHEAD 128
#define HHEADS 32
#define MCACHE 8192
#define SPLITK 16
#define KSLICE (NMODEL / SPLITK)   // 256
#define COLS_PER_BLK 256
#define CHUNK 256
#define NCHUNK (MCACHE / CHUNK)    // 32

// ---------------- Kernel 1: split-K partial QKV projection ----------------
// grid = (NMODEL/COLS_PER_BLK=16, SPLITK=16, 3 mats), block = 256
// Each thread owns one output column, accumulates over a 256-wide K slice.
// W reads fully coalesced (consecutive threads -> consecutive columns).
// X reads are wave-uniform -> scalar loads via K$.
__global__ void qkv_gemm(const float* __restrict__ X,
                         const float* __restrict__ Wq,
                         const float* __restrict__ Wk,
                         const float* __restrict__ Wv,
                         float* __restrict__ part) {
    const int col   = blockIdx.x * COLS_PER_BLK + threadIdx.x;
    const int split = blockIdx.y;
    const int mat   = blockIdx.z;
    const float* W = (mat == 0) ? Wq : (mat == 1) ? Wk : Wv;
    const int k0 = split * KSLICE;

    float acc[S_LEN];
#pragma unroll
    for (int s = 0; s < S_LEN; ++s) acc[s] = 0.f;

    for (int k = 0; k < KSLICE; ++k) {
        const float w = W[(size_t)(k0 + k) * NMODEL + col];
#pragma unroll
        for (int s = 0; s < S_LEN; ++s) {
            acc[s] += X[s * NMODEL + k0 + k] * w;   // uniform addr -> s_load
        }
    }
    // part[mat][split][s][col]
    const size_t base = ((size_t)(mat * SPLITK + split) * S_LEN) * NMODEL + col;
#pragma unroll
    for (int s = 0; s < S_LEN; ++s) part[base + (size_t)s * NMODEL] = acc[s];
}

// ---------------- Kernel 2: reduce split-K partials ----------------
// qkv[mat][s][col] = sum over splits. 3*16*4096 outputs.
__global__ void qkv_reduce(const float* __restrict__ part,
                           float* __restrict__ qkv) {
    const int idx = blockIdx.x * blockDim.x + threadIdx.x;
    const int mat = idx / (S_LEN * NMODEL);
    const int rem = idx % (S_LEN * NMODEL);
    float sum = 0.f;
#pragma unroll
    for (int sp = 0; sp < SPLITK; ++sp) {
        sum += part[(size_t)(mat * SPLITK + sp) * (S_LEN * NMODEL) + rem];
    }
    qkv[idx] = sum;
}

// ---------------- Kernel 3: flash-decode partial attention ----------------
// grid = (NCHUNK=32, HHEADS=32), block = 256 (one thread per cache row in chunk)
__global__ void attn_partial(const float* __restrict__ qkv,
                             const float* __restrict__ cacheK,
                             const float* __restrict__ cacheV,
                             const int* __restrict__ Pp,
                             float* __restrict__ opart,
                             float* __restrict__ mstat,
                             float* __restrict__ lstat) {
    const int c   = blockIdx.x;
    const int h   = blockIdx.y;
    const int tid = threadIdx.x;
    const int P   = *Pp;

    const float* qb = qkv;                        // [s][4096], col = h*128+d
    const float* kb = qkv + S_LEN * NMODEL;       // freshly projected k
    const float* vb = qkv + 2 * S_LEN * NMODEL;   // freshly projected v

    __shared__ float q_s[S_LEN][DHEAD];           // 8 KB
    __shared__ float sc[CHUNK][S_LEN + 1];        // 17.4 KB, pad->conflict-free
    __shared__ float mloc[S_LEN], lloc[S_LEN];

    for (int i = tid; i < S_LEN * DHEAD; i += 256) {
        const int s = i / DHEAD, d = i % DHEAD;
        q_s[s][d] = qb[s * NMODEL + h * DHEAD + d];
    }
    __syncthreads();

    // ---- step 1: scores for this thread's cache row ----
    {
        const int gm = c * CHUNK + tid;
        const float* kr;
        if (gm >= P && gm < P + S_LEN)
            kr = kb + (size_t)(gm - P) * NMODEL + h * DHEAD;   // cache update at P
        else
            kr = cacheK + ((size_t)h * MCACHE + gm) * DHEAD;

        float acc[S_LEN];
#pragma unroll
        for (int s = 0; s < S_LEN; ++s) acc[s] = 0.f;
        for (int dc = 0; dc < DHEAD / 4; ++dc) {
            const float4 kv = *(const float4*)(kr + dc * 4);
#pragma unroll
            for (int s = 0; s < S_LEN; ++s) {
                acc[s] += kv.x * q_s[s][dc * 4 + 0] + kv.y * q_s[s][dc * 4 + 1]
                        + kv.z * q_s[s][dc * 4 + 2] + kv.w * q_s[s][dc * 4 + 3];
            }
        }
#pragma unroll
        for (int s = 0; s < S_LEN; ++s) sc[tid][s] = acc[s];
    }
    __syncthreads();

    // ---- step 2: per-s max & sumexp over the chunk; overwrite sc with exp ----
    {
        const int wv = tid >> 6, lane = tid & 63;
        for (int s4 = 0; s4 < 4; ++s4) {
            const int s = wv * 4 + s4;
            float mx = -1e30f;
#pragma unroll
            for (int r = 0; r < 4; ++r) mx = fmaxf(mx, sc[lane + 64 * r][s]);
            for (int off = 32; off > 0; off >>= 1) mx = fmaxf(mx, __shfl_xor(mx, off, 64));
            float sum = 0.f;
#pragma unroll
            for (int r = 0; r < 4; ++r) {
                const int m = lane + 64 * r;
                const float e = __expf(sc[m][s] - mx);
                sc[m][s] = e;
                sum += e;
            }
            for (int off = 32; off > 0; off >>= 1) sum += __shfl_xor(sum, off, 64);
            if (lane == 0) { mloc[s] = mx; lloc[s] = sum; }
        }
    }
    __syncthreads();

    // ---- step 3: partial output o[s][d] = sum_m p * V[m][d] ----
    {
        const int s  = tid >> 4;
        const int d8 = (tid & 15) * 8;
        float acc[8];
#pragma unroll
        for (int j = 0; j < 8; ++j) acc[j] = 0.f;
        for (int m = 0; m < CHUNK; ++m) {
            const int gm = c * CHUNK + m;
            const float* vr;
            if (gm >= P && gm < P + S_LEN)
                vr = vb + (size_t)(gm - P) * NMODEL + h * DHEAD;
            else
                vr = cacheV + ((size_t)h * MCACHE + gm) * DHEAD;
            const float p = sc[m][s];
            const float4 a = *(const float4*)(vr + d8);
            const float4 b = *(const float4*)(vr + d8 + 4);
            acc[0] += p * a.x; acc[1] += p * a.y; acc[2] += p * a.z; acc[3] += p * a.w;
            acc[4] += p * b.x; acc[5] += p * b.y; acc[6] += p * b.z; acc[7] += p * b.w;
        }
        const size_t ob = (((size_t)h * NCHUNK + c) * S_LEN + s) * DHEAD + d8;
#pragma unroll
        for (int j = 0; j < 8; ++j) opart[ob + j] = acc[j];
    }
    if (tid < S_LEN) {
        mstat[((size_t)h * NCHUNK + c) * S_LEN + tid] = mloc[tid];
        lstat[((size_t)h * NCHUNK + c) * S_LEN + tid] = lloc[tid];
    }
}

// ---------------- Kernel 4: combine chunk partials ----------------
// grid = (S_LEN=16, HHEADS=32), block = 128 (one thread per d)
__global__ void attn_combine(const float* __restrict__ opart,
                             const float* __restrict__ mstat,
                             const float* __restrict__ lstat,
                             float* __restrict__ out) {
    const int d = threadIdx.x;
    const int s = blockIdx.x;
    const int h = blockIdx.y;

    float gmax = -1e30f;
    for (int c = 0; c < NCHUNK; ++c)
        gmax = fmaxf(gmax, mstat[((size_t)h * NCHUNK + c) * S_LEN + s]);

    float L = 0.f, o = 0.f;
    for (int c = 0; c < NCHUNK; ++c) {
        const size_t si = (size_t)h * NCHUNK * S_LEN + (size_t)c * S_LEN + s;
        const float w = __expf(mstat[si] - gmax);
        L += lstat[si] * w;
        o += w * opart[(((size_t)h * NCHUNK + c) * S_LEN + s) * DHEAD + d];
    }
    // output layout: flat [H][S][D] (reference reshapes without transpose)
    out[((size_t)h * S_LEN + s) * DHEAD + d] = o / L;
}

extern "C" void kernel_launch(void* const* d_in, const int* in_sizes, int n_in,
                              void* d_out, int out_size, void* d_ws, size_t ws_size,
                              hipStream_t stream) {
    const float* X      = (const float*)d_in[0];
    const float* Wq     = (const float*)d_in[1];
    const float* Wk     = (const float*)d_in[2];
    const float* Wv     = (const float*)d_in[3];
    const float* cacheK = (const float*)d_in[4];
    const float* cacheV = (const float*)d_in[5];
    const int*   P      = (const int*)d_in[6];
    float* out = (float*)d_out;
    float* ws  = (float*)d_ws;

    // workspace layout (floats)
    float* qkv   = ws;                                   // [3][16][4096]
    float* part  = qkv  + 3 * S_LEN * NMODEL;            // [3][16][16][4096]
    float* opart = part + 3 * SPLITK * S_LEN * NMODEL;   // [32][32][16][128]
    float* mstat = opart + (size_t)HHEADS * NCHUNK * S_LEN * DHEAD;
    float* lstat = mstat + (size_t)HHEADS * NCHUNK * S_LEN;

    qkv_gemm<<<dim3(NMODEL / COLS_PER_BLK, SPLITK, 3), 256, 0, stream>>>(X, Wq, Wk, Wv, part);
    qkv_reduce<<<(3 * S_LEN * NMODEL) / 256, 256, 0, stream>>>(part, qkv);
    attn_partial<<<dim3(NCHUNK, HHEADS), 256, 0, stream>>>(qkv, cacheK, cacheV, P,
                                                           opart, mstat, lstat);
    attn_combine<<<dim3(S_LEN, HHEADS), DHEAD, 0, stream>>>(opart, mstat, lstat, out);
}

// Round 2
// 270.152 us; speedup vs baseline: 1.1552x; 1.1552x over previous
//
#include <hip/hip_runtime.h>

#define S_LEN 16
#define NMODEL 4096
#define DHEAD 128
#define HHEADS 32
#define MCACHE 8192
#define SPLITK 16
#define KSLICE (NMODEL / SPLITK)   // 256
#define CHUNK 128
#define NCHUNK (MCACHE / CHUNK)    // 64

// ---------------- Kernel 1: split-K partial QKV projection ----------------
// grid = (8, SPLITK, 3), block = 256. Thread owns 2 consecutive output cols
// (float2 W loads, coalesced). X K-slice staged in LDS [k][16] (64-B rows,
// wave-uniform ds_read_b128 broadcast). Explicit float2 acc -> registers.
__global__ __launch_bounds__(256) void qkv_gemm(const float* __restrict__ X,
                                                const float* __restrict__ Wq,
                                                const float* __restrict__ Wk,
                                                const float* __restrict__ Wv,
                                                float* __restrict__ part) {
    const int tid   = threadIdx.x;
    const int col2  = blockIdx.x * 256 + tid;   // float2-column index 0..2047
    const int split = blockIdx.y;
    const int mat   = blockIdx.z;
    const float* __restrict__ W = (mat == 0) ? Wq : (mat == 1) ? Wk : Wv;
    const int k0 = split * KSLICE;

    __shared__ float Xs[KSLICE][S_LEN];         // 16 KB, k-major
    for (int i = tid; i < KSLICE * S_LEN; i += 256) {
        const int s = i & 15, k = i >> 4;       // LDS addr = i*4 -> conflict-free
        Xs[k][s] = X[s * NMODEL + k0 + k];      // X is L2-hot (256 KB total)
    }
    __syncthreads();

    float2 acc[S_LEN];
#pragma unroll
    for (int s = 0; s < S_LEN; ++s) { acc[s].x = 0.f; acc[s].y = 0.f; }

    const float2* __restrict__ Wp = (const float2*)(W + (size_t)k0 * NMODEL) + col2;

#pragma unroll 8
    for (int k = 0; k < KSLICE; ++k) {
        const float2 w = Wp[(size_t)k * (NMODEL / 2)];
        const float4* __restrict__ xr = (const float4*)&Xs[k][0];
#pragma unroll
        for (int s4 = 0; s4 < 4; ++s4) {
            const float4 xv = xr[s4];           // uniform addr -> broadcast
            acc[s4 * 4 + 0].x += xv.x * w.x;  acc[s4 * 4 + 0].y += xv.x * w.y;
            acc[s4 * 4 + 1].x += xv.y * w.x;  acc[s4 * 4 + 1].y += xv.y * w.y;
            acc[s4 * 4 + 2].x += xv.z * w.x;  acc[s4 * 4 + 2].y += xv.z * w.y;
            acc[s4 * 4 + 3].x += xv.w * w.x;  acc[s4 * 4 + 3].y += xv.w * w.y;
        }
    }

    float2* __restrict__ pp =
        (float2*)(part + (size_t)(mat * SPLITK + split) * S_LEN * NMODEL) + col2;
#pragma unroll
    for (int s = 0; s < S_LEN; ++s) pp[(size_t)s * (NMODEL / 2)] = acc[s];
}

// ---------------- Kernel 2: reduce split-K partials (float4) ----------------
__global__ __launch_bounds__(256) void qkv_reduce(const float* __restrict__ part,
                                                  float* __restrict__ qkv) {
    const int i4   = blockIdx.x * 256 + threadIdx.x;  // float4 index
    const int flat = i4 * 4;
    const int mat  = flat / (S_LEN * NMODEL);
    const int rem  = flat % (S_LEN * NMODEL);
    float4 sum = {0.f, 0.f, 0.f, 0.f};
#pragma unroll
    for (int sp = 0; sp < SPLITK; ++sp) {
        const float4 v = *(const float4*)(part +
            (size_t)(mat * SPLITK + sp) * (S_LEN * NMODEL) + rem);
        sum.x += v.x; sum.y += v.y; sum.z += v.z; sum.w += v.w;
    }
    *(float4*)(qkv + flat) = sum;
}

// ---------------- Kernel 3: flash-decode partial attention ----------------
// grid = (NCHUNK=64, HHEADS=32), block = 128 (one thread per cache row)
__global__ __launch_bounds__(128) void attn_partial(const float* __restrict__ qkv,
                                                    const float* __restrict__ cacheK,
                                                    const float* __restrict__ cacheV,
                                                    const int* __restrict__ Pp,
                                                    float* __restrict__ opart,
                                                    float* __restrict__ mstat,
                                                    float* __restrict__ lstat) {
    const int c   = blockIdx.x;
    const int h   = blockIdx.y;
    const int tid = threadIdx.x;
    const int P   = *Pp;

    const float* qb = qkv;
    const float* kb = qkv + S_LEN * NMODEL;
    const float* vb = qkv + 2 * S_LEN * NMODEL;

    __shared__ float q_s[S_LEN][DHEAD];          // 8 KB
    __shared__ float sc[CHUNK][S_LEN + 1];       // 8.7 KB, padded
    __shared__ float mloc[S_LEN], lloc[S_LEN];

    for (int i = tid; i < S_LEN * DHEAD; i += 128) {
        q_s[i >> 7][i & 127] = qb[(i >> 7) * NMODEL + h * DHEAD + (i & 127)];
    }
    __syncthreads();

    // ---- scores for this thread's cache row ----
    {
        const int gm = c * CHUNK + tid;
        const float* kr = (gm >= P && gm < P + S_LEN)
            ? kb + (size_t)(gm - P) * NMODEL + h * DHEAD       // virtual cache write
            : cacheK + ((size_t)h * MCACHE + gm) * DHEAD;

        float a[S_LEN];
#pragma unroll
        for (int s = 0; s < S_LEN; ++s) a[s] = 0.f;
        for (int dc = 0; dc < DHEAD / 4; ++dc) {
            const float4 kv = *(const float4*)(kr + dc * 4);
#pragma unroll
            for (int s = 0; s < S_LEN; ++s) {
                a[s] += kv.x * q_s[s][dc * 4 + 0] + kv.y * q_s[s][dc * 4 + 1]
                      + kv.z * q_s[s][dc * 4 + 2] + kv.w * q_s[s][dc * 4 + 3];
            }
        }
#pragma unroll
        for (int s = 0; s < S_LEN; ++s) sc[tid][s] = a[s];
    }
    __syncthreads();

    // ---- per-s max & sumexp over the chunk; sc overwritten with exp ----
    {
        const int wv = tid >> 6, lane = tid & 63;
        for (int s8 = 0; s8 < 8; ++s8) {
            const int s = wv * 8 + s8;
            float mx = fmaxf(sc[lane][s], sc[lane + 64][s]);
            for (int off = 32; off > 0; off >>= 1) mx = fmaxf(mx, __shfl_xor(mx, off, 64));
            const float e0 = __expf(sc[lane][s] - mx);
            const float e1 = __expf(sc[lane + 64][s] - mx);
            sc[lane][s] = e0; sc[lane + 64][s] = e1;
            float sum = e0 + e1;
            for (int off = 32; off > 0; off >>= 1) sum += __shfl_xor(sum, off, 64);
            if (lane == 0) { mloc[s] = mx; lloc[s] = sum; }
        }
    }
    __syncthreads();

    // ---- partial output: thread (s = tid>>3) owns 16 cols at (tid&7)*16 ----
    {
        const int s  = tid >> 3;
        const int d0 = (tid & 7) * 16;
        float a[16];
#pragma unroll
        for (int j = 0; j < 16; ++j) a[j] = 0.f;
        for (int m = 0; m < CHUNK; ++m) {
            const int gm = c * CHUNK + m;
            const float* vr = (gm >= P && gm < P + S_LEN)
                ? vb + (size_t)(gm - P) * NMODEL + h * DHEAD
                : cacheV + ((size_t)h * MCACHE + gm) * DHEAD;
            const float p = sc[m][s];
#pragma unroll
            for (int j = 0; j < 4; ++j) {
                const float4 v = *(const float4*)(vr + d0 + j * 4);
                a[j * 4 + 0] += p * v.x; a[j * 4 + 1] += p * v.y;
                a[j * 4 + 2] += p * v.z; a[j * 4 + 3] += p * v.w;
            }
        }
        const size_t ob = (((size_t)h * NCHUNK + c) * S_LEN + s) * DHEAD + d0;
#pragma unroll
        for (int j = 0; j < 4; ++j) {
            float4 v; v.x = a[j*4+0]; v.y = a[j*4+1]; v.z = a[j*4+2]; v.w = a[j*4+3];
            *(float4*)(opart + ob + j * 4) = v;
        }
    }
    if (tid < S_LEN) {
        mstat[((size_t)h * NCHUNK + c) * S_LEN + tid] = mloc[tid];
        lstat[((size_t)h * NCHUNK + c) * S_LEN + tid] = lloc[tid];
    }
}

// ---------------- Kernel 4: combine chunk partials ----------------
// grid = (S_LEN=16, HHEADS=32), block = 128 (one thread per d)
__global__ __launch_bounds__(128) void attn_combine(const float* __restrict__ opart,
                                                    const float* __restrict__ mstat,
                                                    const float* __restrict__ lstat,
                                                    float* __restrict__ out) {
    const int d = threadIdx.x;
    const int s = blockIdx.x;
    const int h = blockIdx.y;

    float gmax = -1e30f;
    for (int c = 0; c < NCHUNK; ++c)
        gmax = fmaxf(gmax, mstat[((size_t)h * NCHUNK + c) * S_LEN + s]);

    float L = 0.f, o = 0.f;
    for (int c = 0; c < NCHUNK; ++c) {
        const size_t si = (size_t)h * NCHUNK * S_LEN + (size_t)c * S_LEN + s;
        const float w = __expf(mstat[si] - gmax);
        L += lstat[si] * w;
        o += w * opart[si * DHEAD + d];
    }
    out[((size_t)h * S_LEN + s) * DHEAD + d] = o / L;
}

extern "C" void kernel_launch(void* const* d_in, const int* in_sizes, int n_in,
                              void* d_out, int out_size, void* d_ws, size_t ws_size,
                              hipStream_t stream) {
    const float* X      = (const float*)d_in[0];
    const float* Wq     = (const float*)d_in[1];
    const float* Wk     = (const float*)d_in[2];
    const float* Wv     = (const float*)d_in[3];
    const float* cacheK = (const float*)d_in[4];
    const float* cacheV = (const float*)d_in[5];
    const int*   P      = (const int*)d_in[6];
    float* out = (float*)d_out;
    float* ws  = (float*)d_ws;

    // workspace layout (floats); opart ALIASES part (dead after qkv_reduce)
    float* qkv   = ws;                                   // 3*16*4096
    float* part  = qkv + 3 * S_LEN * NMODEL;             // 3*16*16*4096 (50.3 MB)
    float* opart = part;                                 // 32*64*16*128 = 4.19M floats
    float* mstat = opart + (size_t)HHEADS * NCHUNK * S_LEN * DHEAD;
    float* lstat = mstat + (size_t)HHEADS * NCHUNK * S_LEN;

    qkv_gemm<<<dim3(8, SPLITK, 3), 256, 0, stream>>>(X, Wq, Wk, Wv, part);
    qkv_reduce<<<(3 * S_LEN * NMODEL / 4) / 256, 256, 0, stream>>>(part, qkv);
    attn_partial<<<dim3(NCHUNK, HHEADS), 128, 0, stream>>>(qkv, cacheK, cacheV, P,
                                                           opart, mstat, lstat);
    attn_combine<<<dim3(S_LEN, HHEADS), DHEAD, 0, stream>>>(opart, mstat, lstat, out);
}